// Round 5
// baseline (146.609 us; speedup 1.0000x reference)
//
#include <hip/hip_runtime.h>
#include <stdint.h>

#define IN_DIM 4096

typedef float f32x4 __attribute__((ext_vector_type(4)));

// K1: trace update. Streams: read T (+x, 16KB cache-resident), write O1. 1R+1W.
__global__ __launch_bounds__(256) void snn_trace_kernel(
    const int*   __restrict__ x,
    const f32x4* __restrict__ T,
    const float* __restrict__ dtp,
    const float* __restrict__ taup,
    const float* __restrict__ alp,
    f32x4* __restrict__ O1,
    int iters, int nvec)
{
    const float k  = (*dtp) / (*taup);
    const float al = *alp;

    const int tid    = blockIdx.x * blockDim.x + threadIdx.x;
    const int stride = gridDim.x * blockDim.x;

    // stride*4 is a multiple of IN_DIM -> this thread's x slice is loop-invariant
    const int col = (tid * 4) & (IN_DIM - 1);
    const int4 xv = *(const int4*)(x + col);
    const float ax0 = al * (float)xv.x;
    const float ax1 = al * (float)xv.y;
    const float ax2 = al * (float)xv.z;
    const float ax3 = al * (float)xv.w;

    #pragma unroll 4
    for (int it = 0; it < iters; ++it) {
        const int v = tid + it * stride;
        const f32x4 tv = T[v];
        f32x4 n;
        // trace_new = trace + k*(-trace + alpha*x)  (reference op order)
        n.x = tv.x + k * (ax0 - tv.x);
        n.y = tv.y + k * (ax1 - tv.y);
        n.z = tv.z + k * (ax2 - tv.z);
        n.w = tv.w + k * (ax3 - tv.w);
        O1[v] = n;
    }

    const int v = tid + iters * stride;
    if (v < nvec) {
        const int c2 = (v * 4) & (IN_DIM - 1);
        const int4 xt = *(const int4*)(x + c2);
        const f32x4 tv = T[v];
        f32x4 n;
        n.x = tv.x + k * (al * (float)xt.x - tv.x);
        n.y = tv.y + k * (al * (float)xt.y - tv.y);
        n.z = tv.z + k * (al * (float)xt.z - tv.z);
        n.w = tv.w + k * (al * (float)xt.w - tv.w);
        O1[v] = n;
    }
}

// K2: spike gate. Streams: read D, W; write O0. 2R+1W.
__global__ __launch_bounds__(256) void snn_spike_kernel(
    const f32x4* __restrict__ W,
    const f32x4* __restrict__ D,
    f32x4* __restrict__ O0,
    int iters, int nvec)
{
    const int tid    = blockIdx.x * blockDim.x + threadIdx.x;
    const int stride = gridDim.x * blockDim.x;

    #pragma unroll 4
    for (int it = 0; it < iters; ++it) {
        const int v = tid + it * stride;
        const f32x4 wv = W[v];
        const f32x4 dv = D[v];
        f32x4 o;
        // spike = ((d>0 ? d-1 : d) == 1); d is an exact small int
        o.x = ((dv.x > 0.0f ? dv.x - 1.0f : dv.x) == 1.0f) ? wv.x : 0.0f;
        o.y = ((dv.y > 0.0f ? dv.y - 1.0f : dv.y) == 1.0f) ? wv.y : 0.0f;
        o.z = ((dv.z > 0.0f ? dv.z - 1.0f : dv.z) == 1.0f) ? wv.z : 0.0f;
        o.w = ((dv.w > 0.0f ? dv.w - 1.0f : dv.w) == 1.0f) ? wv.w : 0.0f;
        O0[v] = o;
    }

    const int v = tid + iters * stride;
    if (v < nvec) {
        const f32x4 wv = W[v];
        const f32x4 dv = D[v];
        f32x4 o;
        o.x = ((dv.x > 0.0f ? dv.x - 1.0f : dv.x) == 1.0f) ? wv.x : 0.0f;
        o.y = ((dv.y > 0.0f ? dv.y - 1.0f : dv.y) == 1.0f) ? wv.y : 0.0f;
        o.z = ((dv.z > 0.0f ? dv.z - 1.0f : dv.z) == 1.0f) ? wv.z : 0.0f;
        o.w = ((dv.w > 0.0f ? dv.w - 1.0f : dv.w) == 1.0f) ? wv.w : 0.0f;
        O0[v] = o;
    }
}

extern "C" void kernel_launch(void* const* d_in, const int* in_sizes, int n_in,
                              void* d_out, int out_size, void* d_ws, size_t ws_size,
                              hipStream_t stream) {
    // setup_inputs order: x, weight, trace, delay, delay_init(UNUSED), dt, tau_t, alpha_t
    const int*   x  = (const int*)d_in[0];
    const f32x4* W  = (const f32x4*)d_in[1];
    const f32x4* T  = (const f32x4*)d_in[2];
    const f32x4* D  = (const f32x4*)d_in[3];
    // d_in[4] = delay_init: dead in the reference (delay_new is deleted) — never read.
    const float* dtp  = (const float*)d_in[5];
    const float* taup = (const float*)d_in[6];
    const float* alp  = (const float*)d_in[7];

    const int n_elems = in_sizes[1];        // OUT*IN = 33,554,432
    const int nvec    = n_elems / 4;

    f32x4* O0 = (f32x4*)d_out;
    f32x4* O1 = (f32x4*)((float*)d_out + n_elems);

    const int block  = 256;
    const int grid   = 2048;
    const int stride = grid * block;
    const int iters  = nvec / stride;       // 16 for the bench shape

    // Two sequential kernels with clean stream mixes:
    //   K1 = 1R+1W (copy-like), K2 = 2R+1W. Tests whether the flat 133 us is a
    //   stream-mix penalty (expect ~115 us) or a total-traffic ceiling (unchanged).
    snn_trace_kernel<<<grid, block, 0, stream>>>(x, T, dtp, taup, alp, O1, iters, nvec);
    snn_spike_kernel<<<grid, block, 0, stream>>>(W, D, O0, iters, nvec);
}

// Round 6
// 121.108 us; speedup vs baseline: 1.2106x; 1.2106x over previous
//
#include <hip/hip_runtime.h>
#include <stdint.h>

#define IN_DIM 4096

typedef float f32x4 __attribute__((ext_vector_type(4)));

__global__ __launch_bounds__(256) void snn_step_kernel(
    const int*   __restrict__ x,    // (IN,1) int32 binary spikes
    const f32x4* __restrict__ W,    // (OUT,IN) f32, 4 elems per vec
    const f32x4* __restrict__ T,    // trace
    const f32x4* __restrict__ D,    // delay (small non-negative ints as f32)
    const float* __restrict__ dtp,
    const float* __restrict__ taup,
    const float* __restrict__ alp,
    f32x4* __restrict__ O0,         // weight * spike_out
    f32x4* __restrict__ O1,         // trace_new
    int iters, int nvec)
{
    const float k  = (*dtp) / (*taup);  // dt/tau
    const float al = *alp;

    const int tid    = blockIdx.x * blockDim.x + threadIdx.x;
    const int stride = gridDim.x * blockDim.x;

    // stride*4 floats is a multiple of IN_DIM -> x slice is loop-invariant.
    const int col = (tid * 4) & (IN_DIM - 1);
    const int4 xv = *(const int4*)(x + col);
    const float ax0 = al * (float)xv.x;
    const float ax1 = al * (float)xv.y;
    const float ax2 = al * (float)xv.z;
    const float ax3 = al * (float)xv.w;

    #pragma unroll 4
    for (int it = 0; it < iters; ++it) {
        const int v = tid + it * stride;
        // Non-temporal: single-use streaming data; bypass LLC retention so the
        // cache isn't churned by 671 MB/replay of dead lines.
        const f32x4 wv = __builtin_nontemporal_load(W + v);
        const f32x4 tv = __builtin_nontemporal_load(T + v);
        const f32x4 dv = __builtin_nontemporal_load(D + v);

        f32x4 o, n;
        // trace_new = trace + k*(-trace + alpha*x)  (reference op order)
        n.x = tv.x + k * (ax0 - tv.x);
        n.y = tv.y + k * (ax1 - tv.y);
        n.z = tv.z + k * (ax2 - tv.z);
        n.w = tv.w + k * (ax3 - tv.w);
        // spike = ((d>0 ? d-1 : d) == 1); d is an exact small int
        o.x = ((dv.x > 0.0f ? dv.x - 1.0f : dv.x) == 1.0f) ? wv.x : 0.0f;
        o.y = ((dv.y > 0.0f ? dv.y - 1.0f : dv.y) == 1.0f) ? wv.y : 0.0f;
        o.z = ((dv.z > 0.0f ? dv.z - 1.0f : dv.z) == 1.0f) ? wv.z : 0.0f;
        o.w = ((dv.w > 0.0f ? dv.w - 1.0f : dv.w) == 1.0f) ? wv.w : 0.0f;

        __builtin_nontemporal_store(o, O0 + v);
        __builtin_nontemporal_store(n, O1 + v);
    }

    // Tail (not taken for the bench shape: nvec == iters * stride)
    const int v = tid + iters * stride;
    if (v < nvec) {
        const int c2 = (v * 4) & (IN_DIM - 1);
        const int4 xt = *(const int4*)(x + c2);
        const f32x4 wv = W[v];
        const f32x4 tv = T[v];
        const f32x4 dv = D[v];
        f32x4 o, n;
        n.x = tv.x + k * (al * (float)xt.x - tv.x);
        n.y = tv.y + k * (al * (float)xt.y - tv.y);
        n.z = tv.z + k * (al * (float)xt.z - tv.z);
        n.w = tv.w + k * (al * (float)xt.w - tv.w);
        o.x = ((dv.x > 0.0f ? dv.x - 1.0f : dv.x) == 1.0f) ? wv.x : 0.0f;
        o.y = ((dv.y > 0.0f ? dv.y - 1.0f : dv.y) == 1.0f) ? wv.y : 0.0f;
        o.z = ((dv.z > 0.0f ? dv.z - 1.0f : dv.z) == 1.0f) ? wv.z : 0.0f;
        o.w = ((dv.w > 0.0f ? dv.w - 1.0f : dv.w) == 1.0f) ? wv.w : 0.0f;
        O0[v] = o;
        O1[v] = n;
    }
}

extern "C" void kernel_launch(void* const* d_in, const int* in_sizes, int n_in,
                              void* d_out, int out_size, void* d_ws, size_t ws_size,
                              hipStream_t stream) {
    // setup_inputs order: x, weight, trace, delay, delay_init(UNUSED), dt, tau_t, alpha_t
    const int*   x  = (const int*)d_in[0];
    const f32x4* W  = (const f32x4*)d_in[1];
    const f32x4* T  = (const f32x4*)d_in[2];
    const f32x4* D  = (const f32x4*)d_in[3];
    // d_in[4] = delay_init: dead in the reference (delay_new is deleted) — never read.
    const float* dtp  = (const float*)d_in[5];
    const float* taup = (const float*)d_in[6];
    const float* alp  = (const float*)d_in[7];

    const int n_elems = in_sizes[1];        // OUT*IN = 33,554,432
    const int nvec    = n_elems / 4;

    f32x4* O0 = (f32x4*)d_out;
    f32x4* O1 = (f32x4*)((float*)d_out + n_elems);

    const int block  = 256;
    const int grid   = 2048;                // best-known config (rounds 2-4 flat)
    const int stride = grid * block;
    const int iters  = nvec / stride;       // 16 for the bench shape
    snn_step_kernel<<<grid, block, 0, stream>>>(x, W, T, D, dtp, taup, alp,
                                                O0, O1, iters, nvec);
}